// Round 5
// baseline (4573.586 us; speedup 1.0000x reference)
//
#include <hip/hip_runtime.h>
#include <cstdint>
#include <cstddef>

// ---------------------------------------------------------------------------
// GCN: 5 layers, out = Â (x W) + b per layer, SiLU on layers 0-3.
// Â = D^-1/2 (A + I) D^-1/2 built from edge_index with self-loops.
//  - aggregate in the LOWEST-dim space (linearity): layer 0 aggregates the
//    3-dim input; layer 4's 128->3 matmul is fused into layer 3's GEMM
//    epilogue (PROJ) so layer 4 aggregates 3-dim.
//  - CSR build via LDS-binned multisplit.
//  - 128-dim aggregation: column-blocked layout [8][N][16] + XCD-pinned
//    slices (blockIdx%8 -> XCD): each XCD's random-gather working set is a
//    3.2 MB slice resident in its own 4 MB L2.  (Round-4 lesson: row-major
//    gather streams 228 MB/dispatch through L2 at 55% hit.)
//  - GEMM: W (64 KB) resident in LDS, barrier-free main loop.
// ---------------------------------------------------------------------------

#define NB_SPLIT 256          // workgroups in prep/split passes
#define BUCKET_SHIFT 7        // 128 nodes per bucket

static __device__ __forceinline__ float silu_f(float x) {
  return x / (1.0f + __expf(-x));
}

// Detect whether edge_index is stored as int64 (odd int32 words all zero) or
// int32. flag = 1 -> int64 layout, 0 -> int32 layout.
__global__ void k_detect(const int* __restrict__ e32, int* __restrict__ flag) {
  __shared__ int any_nonzero;
  if (threadIdx.x == 0) any_nonzero = 0;
  __syncthreads();
  int v = e32[threadIdx.x * 2 + 1];
  if (v != 0) any_nonzero = 1;
  __syncthreads();
  if (threadIdx.x == 0) *flag = (any_nonzero ? 0 : 1);
}

// Pass A: pack edges to 4B records + per-(bucket, wg) histogram.
__global__ __launch_bounds__(256) void k_prep(
    const int* __restrict__ e32, const int* __restrict__ flag,
    int* __restrict__ epack, int* __restrict__ cnt2,
    int E, int nbucket, int chunk) {
  __shared__ int hist[512];
  const int w = blockIdx.x, t = threadIdx.x;
  for (int b = t; b < nbucket; b += 256) hist[b] = 0;
  __syncthreads();
  const int f = *flag;
  const int i0 = w * chunk;
  const int i1 = min(E, i0 + chunk);
  for (int i = i0 + t; i < i1; i += 256) {
    int s, d;
    if (f) { s = e32[2 * i]; d = e32[2 * E + 2 * i]; }
    else   { s = e32[i];     d = e32[E + i]; }
    epack[i] = s | (d << 16);            // requires N <= 65536 (N = 50000)
    atomicAdd(&hist[d >> BUCKET_SHIFT], 1);
  }
  __syncthreads();
  for (int b = t; b < nbucket; b += 256) cnt2[b * NB_SPLIT + w] = hist[b];
}

// Hierarchical exclusive scan, stage 1: 1024 elems/block (4/thread).
__global__ void k_scan1(const int* __restrict__ cnt, int* __restrict__ outp,
                        int* __restrict__ bsum, int n) {
  __shared__ int wsum[4];
  const int t = threadIdx.x;
  const int base = blockIdx.x * 1024 + t * 4;
  int v0 = 0, v1 = 0, v2 = 0, v3 = 0;
  if (base + 0 < n) v0 = cnt[base + 0];
  if (base + 1 < n) v1 = cnt[base + 1];
  if (base + 2 < n) v2 = cnt[base + 2];
  if (base + 3 < n) v3 = cnt[base + 3];
  const int s = v0 + v1 + v2 + v3;
  int sc = s;
  const int lane = t & 63;
  #pragma unroll
  for (int o = 1; o < 64; o <<= 1) {
    int u = __shfl_up(sc, o);
    if (lane >= o) sc += u;
  }
  const int wid = t >> 6;
  if (lane == 63) wsum[wid] = sc;
  __syncthreads();
  int wbase = 0;
  for (int w = 0; w < wid; ++w) wbase += wsum[w];
  const int ex = wbase + sc - s;
  if (base + 0 < n) outp[base + 0] = ex;
  if (base + 1 < n) outp[base + 1] = ex + v0;
  if (base + 2 < n) outp[base + 2] = ex + v0 + v1;
  if (base + 3 < n) outp[base + 3] = ex + v0 + v1 + v2;
  if (t == 0) bsum[blockIdx.x] = wsum[0] + wsum[1] + wsum[2] + wsum[3];
}

// Stage 2: serial exclusive scan of block sums (small).
__global__ void k_scan2(int* __restrict__ bsum, int nblk) {
  if (threadIdx.x == 0 && blockIdx.x == 0) {
    int acc = 0;
    for (int i = 0; i < nblk; ++i) { int v = bsum[i]; bsum[i] = acc; acc += v; }
  }
}

// Stage 3: add block offsets.
__global__ void k_scanadd(int* __restrict__ arr, const int* __restrict__ bsum, int n) {
  int i = blockIdx.x * blockDim.x + threadIdx.x;
  if (i < n) arr[i] += bsum[i >> 10];
}

// Pass B: scatter packed edges into bucket-grouped tmp; each (wg,bucket) owns
// a private contiguous sub-region -> L2 merges the 4B writes into full lines.
__global__ __launch_bounds__(256) void k_split(
    const int* __restrict__ epack, const int* __restrict__ off2,
    int* __restrict__ tmp, int E, int nbucket, int chunk) {
  __shared__ int cur[512];
  const int w = blockIdx.x, t = threadIdx.x;
  for (int b = t; b < nbucket; b += 256) cur[b] = off2[b * NB_SPLIT + w];
  __syncthreads();
  const int i0 = w * chunk;
  const int i1 = min(E, i0 + chunk);
  for (int i = i0 + t; i < i1; i += 256) {
    int p = epack[i];
    int b = (int)(((unsigned)p) >> (16 + BUCKET_SHIFT));
    int pos = atomicAdd(&cur[b], 1);
    tmp[pos] = p;
  }
}

// Pass C: one wg per bucket. Counts per-node degree from the bucket's edge
// stream (LDS), scans it (128-wide), writes rowp + dis, then places edges.
__global__ __launch_bounds__(256) void k_csr(
    const int* __restrict__ tmp, const int* __restrict__ off2,
    int* __restrict__ rowp, float* __restrict__ dis, int* __restrict__ col,
    int E, int nbucket, int N) {
  __shared__ int lcnt[128];
  __shared__ int lcur[128];
  __shared__ int wtot;
  const int b = blockIdx.x, t = threadIdx.x;
  const int nb0 = b << BUCKET_SHIFT;
  const int nn = min(1 << BUCKET_SHIFT, N - nb0);
  if (t < 128) lcnt[t] = 0;
  __syncthreads();
  const int s0 = off2[b * NB_SPLIT];
  const int s1 = (b + 1 < nbucket) ? off2[(b + 1) * NB_SPLIT] : E;
  for (int i = s0 + t; i < s1; i += 256) {
    atomicAdd(&lcnt[((unsigned)tmp[i] >> 16) & 127u], 1);
  }
  __syncthreads();
  int v = 0, sc = 0;
  if (t < 128) {
    v = lcnt[t];
    sc = v;
    #pragma unroll
    for (int o = 1; o < 64; o <<= 1) {
      int u = __shfl_up(sc, o);
      if ((t & 63) >= o) sc += u;
    }
    if (t == 63) wtot = sc;          // wave-0 inclusive total
  }
  __syncthreads();
  if (t < 128) {
    int ex = s0 + ((t >= 64) ? wtot : 0) + sc - v;   // exclusive prefix
    lcur[t] = ex;
    if (t < nn) {
      rowp[nb0 + t] = ex;
      dis[nb0 + t] = rsqrtf((float)(v + 1));
    }
  }
  if (t == 0) rowp[nb0 + nn] = s1;   // bucket end (== next bucket's start)
  __syncthreads();
  for (int i = s0 + t; i < s1; i += 256) {
    unsigned p = (unsigned)tmp[i];
    int j = (int)((p >> 16) & ((1u << BUCKET_SHIFT) - 1));
    int pos = atomicAdd(&lcur[j], 1);
    col[pos] = (int)(p & 0xffffu);
  }
}

// 3-dim aggregation.
// PRESCALE=1: out3[i] = dis[i] * (sum_e in3[s]*dis[s] + in3[i]*dis[i])
// PRESCALE=0: out3[i] = bias + dis[i] * (sum_e in3[s] + in3[i])   (in3 pre-scaled)
template <int PRESCALE>
__global__ void k_agg3(const float* __restrict__ in3, float* __restrict__ out3,
                       const int* __restrict__ rowp, const int* __restrict__ col,
                       const float* __restrict__ dis, const float* __restrict__ bias,
                       int n) {
  int i = blockIdx.x * blockDim.x + threadIdx.x;
  if (i >= n) return;
  const float di = dis[i];
  float a0, a1, a2;
  if (PRESCALE) {
    a0 = in3[i * 3 + 0] * di; a1 = in3[i * 3 + 1] * di; a2 = in3[i * 3 + 2] * di;
  } else {
    a0 = in3[i * 3 + 0]; a1 = in3[i * 3 + 1]; a2 = in3[i * 3 + 2];
  }
  const int e0 = rowp[i], e1 = rowp[i + 1];
  for (int e = e0; e < e1; ++e) {
    int s = col[e];
    if (PRESCALE) {
      float ds_ = dis[s];
      a0 += in3[s * 3 + 0] * ds_;
      a1 += in3[s * 3 + 1] * ds_;
      a2 += in3[s * 3 + 2] * ds_;
    } else {
      a0 += in3[s * 3 + 0];
      a1 += in3[s * 3 + 1];
      a2 += in3[s * 3 + 2];
    }
  }
  a0 *= di; a1 *= di; a2 *= di;
  if (!PRESCALE && bias) { a0 += bias[0]; a1 += bias[1]; a2 += bias[2]; }
  out3[i * 3 + 0] = a0;
  out3[i * 3 + 1] = a1;
  out3[i * 3 + 2] = a2;
}

// Layer 0 matmul: xs = silu(y3 @ W0 + b0) * dis, output in blocked layout.
__global__ void k_mm0(const float* __restrict__ y3, const float* __restrict__ W0,
                      const float* __restrict__ b0, const float* __restrict__ dis,
                      float* __restrict__ out, int n, int slStride) {
  int gid = blockIdx.x * blockDim.x + threadIdx.x;
  int node = gid >> 5;
  int c = (gid & 31) << 2;
  if (node >= n) return;
  float v0 = y3[node * 3 + 0], v1 = y3[node * 3 + 1], v2 = y3[node * 3 + 2];
  float4 a  = *reinterpret_cast<const float4*>(b0 + c);
  float4 w0 = *reinterpret_cast<const float4*>(W0 + 0 * 128 + c);
  float4 w1 = *reinterpret_cast<const float4*>(W0 + 1 * 128 + c);
  float4 w2 = *reinterpret_cast<const float4*>(W0 + 2 * 128 + c);
  a.x += v0 * w0.x + v1 * w1.x + v2 * w2.x;
  a.y += v0 * w0.y + v1 * w1.y + v2 * w2.y;
  a.z += v0 * w0.z + v1 * w1.z + v2 * w2.z;
  a.w += v0 * w0.w + v1 * w1.w + v2 * w2.w;
  const float d = dis[node];
  a.x = silu_f(a.x) * d; a.y = silu_f(a.y) * d;
  a.z = silu_f(a.z) * d; a.w = silu_f(a.w) * d;
  *reinterpret_cast<float4*>(out + (size_t)(c >> 4) * slStride +
                             (size_t)node * 16 + (c & 15)) = a;
}

// 128-dim aggregation, column-sliced: blockIdx = nb*8 + s; dispatch round-robin
// puts all of slice s on XCD s, whose 3.2 MB slice is L2-resident.
// Wave = one (node, slice): 16 edges in flight (4 lanes x float4 each),
// butterfly reduce over group bits, lanes 0-3 store the 64 B result.
__global__ __launch_bounds__(1024) void k_agg_slice(
    const float* __restrict__ xs, float* __restrict__ y,
    const int* __restrict__ rowp, const int* __restrict__ col,
    const float* __restrict__ dis, int n, int slStride) {
  const int s = blockIdx.x & 7;
  const int nb = blockIdx.x >> 3;
  const int lane = threadIdx.x & 63;
  const int node = nb * 16 + (threadIdx.x >> 6);
  if (node >= n) return;
  const int g = lane >> 2;           // edge slot 0..15
  const int c4 = (lane & 3) << 2;    // col offset within slice
  const float* __restrict__ xb = xs + (size_t)s * slStride + c4;
  const int e0 = rowp[node], e1 = rowp[node + 1];
  float4 acc = make_float4(0.f, 0.f, 0.f, 0.f);
  for (int e = e0 + g; e < e1; e += 16) {
    int src = col[e];
    float4 v = *reinterpret_cast<const float4*>(xb + (size_t)src * 16);
    acc.x += v.x; acc.y += v.y; acc.z += v.z; acc.w += v.w;
  }
  #pragma unroll
  for (int o = 4; o <= 32; o <<= 1) {
    acc.x += __shfl_xor(acc.x, o);
    acc.y += __shfl_xor(acc.y, o);
    acc.z += __shfl_xor(acc.z, o);
    acc.w += __shfl_xor(acc.w, o);
  }
  if (lane < 4) {
    float4 self = *reinterpret_cast<const float4*>(xb + (size_t)node * 16);
    const float d = dis[node];
    float4 r;
    r.x = (acc.x + self.x) * d;
    r.y = (acc.y + self.y) * d;
    r.z = (acc.z + self.z) * d;
    r.w = (acc.w + self.w) * d;
    *reinterpret_cast<float4*>(y + (size_t)s * slStride + (size_t)node * 16 + c4) = r;
  }
}

// Middle matmul: h = silu(x @ W + b) * dis.  W (64 KB) resident in LDS, staged
// once; main loop has NO barriers. 512 threads, 64-row tile, thread = 4r x 4c.
// x in blocked layout [8][N][16]. PROJ=1: also project h @ W4 (128->3) and
// store only the 3-dim (row-major) result.
template <int PROJ>
__global__ __launch_bounds__(512) void k_mm_w(
    const float* __restrict__ x, const float* __restrict__ W,
    const float* __restrict__ bias, const float* __restrict__ dis,
    float* __restrict__ out, const float* __restrict__ W4, int n, int slStride) {
  __shared__ float ws[128][128];
  const int t = threadIdx.x;
  #pragma unroll
  for (int it = 0; it < 8; ++it) {
    int i = t + it * 512;            // float4 index over 128x128
    *reinterpret_cast<float4*>(&ws[i >> 5][(i & 31) << 2]) =
        *reinterpret_cast<const float4*>(W + (size_t)i * 4);
  }
  __syncthreads();

  const int tc = (t & 31) << 2;      // 4 cols
  const int tr = (t >> 5) << 2;      // 4 rows within the 64-row tile
  const int row0 = blockIdx.x * 64;

  size_t rbase[4];
  #pragma unroll
  for (int r = 0; r < 4; ++r) {
    rbase[r] = (size_t)min(row0 + tr + r, n - 1) * 16;  // clamped; discarded
  }

  float4 acc[4];
  #pragma unroll
  for (int r = 0; r < 4; ++r) acc[r] = make_float4(0.f, 0.f, 0.f, 0.f);

  #pragma unroll
  for (int sb = 0; sb < 8; ++sb) {
    const float* __restrict__ xb0 = x + (size_t)sb * slStride;
    #pragma unroll
    for (int k2 = 0; k2 < 16; k2 += 4) {
      const int kk = sb * 16 + k2;
      float4 w0 = *reinterpret_cast<const float4*>(&ws[kk + 0][tc]);
      float4 w1 = *reinterpret_cast<const float4*>(&ws[kk + 1][tc]);
      float4 w2 = *reinterpret_cast<const float4*>(&ws[kk + 2][tc]);
      float4 w3 = *reinterpret_cast<const float4*>(&ws[kk + 3][tc]);
      #pragma unroll
      for (int r = 0; r < 4; ++r) {
        float4 xr = *reinterpret_cast<const float4*>(xb0 + rbase[r] + k2);
        acc[r].x += xr.x * w0.x + xr.y * w1.x + xr.z * w2.x + xr.w * w3.x;
        acc[r].y += xr.x * w0.y + xr.y * w1.y + xr.z * w2.y + xr.w * w3.y;
        acc[r].z += xr.x * w0.z + xr.y * w1.z + xr.z * w2.z + xr.w * w3.z;
        acc[r].w += xr.x * w0.w + xr.y * w1.w + xr.z * w2.w + xr.w * w3.w;
      }
    }
  }

  float4 bb = *reinterpret_cast<const float4*>(bias + tc);
  if (PROJ) {
    float w4r[4][3];
    #pragma unroll
    for (int c = 0; c < 4; ++c) {
      w4r[c][0] = W4[(tc + c) * 3 + 0];
      w4r[c][1] = W4[(tc + c) * 3 + 1];
      w4r[c][2] = W4[(tc + c) * 3 + 2];
    }
    #pragma unroll
    for (int r = 0; r < 4; ++r) {
      int row = row0 + tr + r;
      float d = (row < n) ? dis[row] : 0.0f;
      float4 a = acc[r];
      a.x = silu_f(a.x + bb.x) * d;
      a.y = silu_f(a.y + bb.y) * d;
      a.z = silu_f(a.z + bb.z) * d;
      a.w = silu_f(a.w + bb.w) * d;
      float p0 = a.x * w4r[0][0] + a.y * w4r[1][0] + a.z * w4r[2][0] + a.w * w4r[3][0];
      float p1 = a.x * w4r[0][1] + a.y * w4r[1][1] + a.z * w4r[2][1] + a.w * w4r[3][1];
      float p2 = a.x * w4r[0][2] + a.y * w4r[1][2] + a.z * w4r[2][2] + a.w * w4r[3][2];
      #pragma unroll
      for (int m = 16; m >= 1; m >>= 1) {
        p0 += __shfl_xor(p0, m);
        p1 += __shfl_xor(p1, m);
        p2 += __shfl_xor(p2, m);
      }
      if ((t & 31) == 0 && row < n) {
        out[row * 3 + 0] = p0;
        out[row * 3 + 1] = p1;
        out[row * 3 + 2] = p2;
      }
    }
  } else {
    #pragma unroll
    for (int r = 0; r < 4; ++r) {
      int row = row0 + tr + r;
      if (row < n) {
        float4 a = acc[r];
        float d = dis[row];
        a.x = silu_f(a.x + bb.x) * d;
        a.y = silu_f(a.y + bb.y) * d;
        a.z = silu_f(a.z + bb.z) * d;
        a.w = silu_f(a.w + bb.w) * d;
        *reinterpret_cast<float4*>(out + (size_t)(tc >> 4) * slStride +
                                   (size_t)row * 16 + (tc & 15)) = a;
      }
    }
  }
}

extern "C" void kernel_launch(void* const* d_in, const int* in_sizes, int n_in,
                              void* d_out, int out_size, void* d_ws, size_t ws_size,
                              hipStream_t stream) {
  const float* pos = (const float*)d_in[0];
  const int* e32 = (const int*)d_in[1];
  const float* W[5] = {(const float*)d_in[2], (const float*)d_in[4], (const float*)d_in[6],
                       (const float*)d_in[8], (const float*)d_in[10]};
  const float* B[5] = {(const float*)d_in[3], (const float*)d_in[5], (const float*)d_in[7],
                       (const float*)d_in[9], (const float*)d_in[11]};
  float* out = (float*)d_out;

  const int N = in_sizes[0] / 3;
  const int E = in_sizes[1] / 2;
  const int NBUCKET = (N + (1 << BUCKET_SHIFT) - 1) >> BUCKET_SHIFT;  // 391
  const int M = NBUCKET * NB_SPLIT;
  const int chunk = (E + NB_SPLIT - 1) / NB_SPLIT;
  const int slStride = N * 16;           // floats per 16-col slice

  char* base = (char*)d_ws;
  size_t off = 0;
  auto alloc = [&](size_t bytes) -> void* {
    void* p = base + off;
    off += (bytes + 255) & ~(size_t)255;
    return p;
  };
  float* dis   = (float*)alloc((size_t)N * 4);
  int* rowp    = (int*)alloc((size_t)(N + 1) * 4);
  int* bsum2   = (int*)alloc(128 * 4);
  int* flag    = (int*)alloc(256);
  int* cnt2    = (int*)alloc((size_t)M * 4);
  int* off2    = (int*)alloc((size_t)M * 4);
  int* col     = (int*)alloc((size_t)E * 4);
  float* y3    = (float*)alloc((size_t)N * 3 * 4);
  float* bufA  = (float*)alloc((size_t)N * 128 * 4);
  float* bufB  = (float*)alloc((size_t)N * 128 * 4);
  // epack/tmp only live during CSR build; alias the big activation buffers.
  int* epack = (int*)bufA;
  int* tmp   = (int*)bufB;

  const int nblk2 = (M + 1023) / 1024;   // 98

  // --- CSR build ---
  k_detect<<<1, 256, 0, stream>>>(e32, flag);
  k_prep<<<NB_SPLIT, 256, 0, stream>>>(e32, flag, epack, cnt2, E, NBUCKET, chunk);
  k_scan1<<<nblk2, 256, 0, stream>>>(cnt2, off2, bsum2, M);
  k_scan2<<<1, 64, 0, stream>>>(bsum2, nblk2);
  k_scanadd<<<(M + 255) / 256, 256, 0, stream>>>(off2, bsum2, M);
  k_split<<<NB_SPLIT, 256, 0, stream>>>(epack, off2, tmp, E, NBUCKET, chunk);
  k_csr<<<NBUCKET, 256, 0, stream>>>(tmp, off2, rowp, dis, col, E, NBUCKET, N);

  // --- layer 0: 3-dim aggregate (prescale fused) then 3->128 matmul ---
  k_agg3<1><<<(N + 255) / 256, 256, 0, stream>>>(pos, y3, rowp, col, dis, nullptr, N);
  k_mm0<<<(N * 32 + 255) / 256, 256, 0, stream>>>(y3, W[0], B[0], dis, bufA, N, slStride);

  // --- layers 1..2: sliced aggregate (128) then 128x128 matmul + SiLU + dis ---
  const int agg_grid = ((N + 15) / 16) * 8;
  const int mm_grid = (N + 63) / 64;
  for (int l = 1; l <= 2; ++l) {
    k_agg_slice<<<agg_grid, 1024, 0, stream>>>(bufA, bufB, rowp, col, dis, N, slStride);
    k_mm_w<0><<<mm_grid, 512, 0, stream>>>(bufB, W[l], B[l], dis, bufA, nullptr, N, slStride);
  }

  // --- layer 3: aggregate, matmul fused with layer-4's 128->3 projection ---
  k_agg_slice<<<agg_grid, 1024, 0, stream>>>(bufA, bufB, rowp, col, dis, N, slStride);
  k_mm_w<1><<<mm_grid, 512, 0, stream>>>(bufB, W[3], B[3], dis, y3, W[4], N, slStride);

  // --- layer 4: 3-dim aggregate + bias ---
  k_agg3<0><<<(N + 255) / 256, 256, 0, stream>>>(y3, out, rowp, col, dis, B[4], N);

  (void)n_in; (void)out_size; (void)ws_size;
}

// Round 6
// 555.153 us; speedup vs baseline: 8.2384x; 8.2384x over previous
//
#include <hip/hip_runtime.h>
#include <cstdint>
#include <cstddef>

// ---------------------------------------------------------------------------
// GCN: 5 layers, out = Â (x W) + b per layer, SiLU on layers 0-3.
// Â = D^-1/2 (A + I) D^-1/2 built from edge_index with self-loops.
//  - aggregate in the LOWEST-dim space (linearity): layer 0 aggregates the
//    3-dim input; layer 4's 128->3 matmul is fused into layer 3's GEMM
//    epilogue (PROJ) so layer 4 aggregates 3-dim.
//  - CSR build via LDS-binned multisplit.
//  - 128-dim aggregation: column-blocked layout [8][N][16] + XCD-pinned
//    slices (blockIdx%8 -> XCD): each XCD's random-gather working set is a
//    3.2 MB slice resident in its own 4 MB L2.
//  - GEMM: W (64 KB) resident in LDS, barrier-free main loop, unroll 2 ONLY
//    (Round-5 lesson: full 32x unroll -> load clustering -> scratch spill ->
//    3.7 GB spill traffic, 20x regression).
// ---------------------------------------------------------------------------

#define NB_SPLIT 256          // workgroups in prep/split passes
#define BUCKET_SHIFT 7        // 128 nodes per bucket

static __device__ __forceinline__ float silu_f(float x) {
  return x / (1.0f + __expf(-x));
}

// Detect whether edge_index is stored as int64 (odd int32 words all zero) or
// int32. flag = 1 -> int64 layout, 0 -> int32 layout.
__global__ void k_detect(const int* __restrict__ e32, int* __restrict__ flag) {
  __shared__ int any_nonzero;
  if (threadIdx.x == 0) any_nonzero = 0;
  __syncthreads();
  int v = e32[threadIdx.x * 2 + 1];
  if (v != 0) any_nonzero = 1;
  __syncthreads();
  if (threadIdx.x == 0) *flag = (any_nonzero ? 0 : 1);
}

// Pass A: pack edges to 4B records + per-(bucket, wg) histogram.
__global__ __launch_bounds__(256) void k_prep(
    const int* __restrict__ e32, const int* __restrict__ flag,
    int* __restrict__ epack, int* __restrict__ cnt2,
    int E, int nbucket, int chunk) {
  __shared__ int hist[512];
  const int w = blockIdx.x, t = threadIdx.x;
  for (int b = t; b < nbucket; b += 256) hist[b] = 0;
  __syncthreads();
  const int f = *flag;
  const int i0 = w * chunk;
  const int i1 = min(E, i0 + chunk);
  for (int i = i0 + t; i < i1; i += 256) {
    int s, d;
    if (f) { s = e32[2 * i]; d = e32[2 * E + 2 * i]; }
    else   { s = e32[i];     d = e32[E + i]; }
    epack[i] = s | (d << 16);            // requires N <= 65536 (N = 50000)
    atomicAdd(&hist[d >> BUCKET_SHIFT], 1);
  }
  __syncthreads();
  for (int b = t; b < nbucket; b += 256) cnt2[b * NB_SPLIT + w] = hist[b];
}

// Hierarchical exclusive scan, stage 1: 1024 elems/block (4/thread).
__global__ void k_scan1(const int* __restrict__ cnt, int* __restrict__ outp,
                        int* __restrict__ bsum, int n) {
  __shared__ int wsum[4];
  const int t = threadIdx.x;
  const int base = blockIdx.x * 1024 + t * 4;
  int v0 = 0, v1 = 0, v2 = 0, v3 = 0;
  if (base + 0 < n) v0 = cnt[base + 0];
  if (base + 1 < n) v1 = cnt[base + 1];
  if (base + 2 < n) v2 = cnt[base + 2];
  if (base + 3 < n) v3 = cnt[base + 3];
  const int s = v0 + v1 + v2 + v3;
  int sc = s;
  const int lane = t & 63;
  #pragma unroll
  for (int o = 1; o < 64; o <<= 1) {
    int u = __shfl_up(sc, o);
    if (lane >= o) sc += u;
  }
  const int wid = t >> 6;
  if (lane == 63) wsum[wid] = sc;
  __syncthreads();
  int wbase = 0;
  for (int w = 0; w < wid; ++w) wbase += wsum[w];
  const int ex = wbase + sc - s;
  if (base + 0 < n) outp[base + 0] = ex;
  if (base + 1 < n) outp[base + 1] = ex + v0;
  if (base + 2 < n) outp[base + 2] = ex + v0 + v1;
  if (base + 3 < n) outp[base + 3] = ex + v0 + v1 + v2;
  if (t == 0) bsum[blockIdx.x] = wsum[0] + wsum[1] + wsum[2] + wsum[3];
}

// Stage 2: serial exclusive scan of block sums (small).
__global__ void k_scan2(int* __restrict__ bsum, int nblk) {
  if (threadIdx.x == 0 && blockIdx.x == 0) {
    int acc = 0;
    for (int i = 0; i < nblk; ++i) { int v = bsum[i]; bsum[i] = acc; acc += v; }
  }
}

// Stage 3: add block offsets.
__global__ void k_scanadd(int* __restrict__ arr, const int* __restrict__ bsum, int n) {
  int i = blockIdx.x * blockDim.x + threadIdx.x;
  if (i < n) arr[i] += bsum[i >> 10];
}

// Pass B: scatter packed edges into bucket-grouped tmp; each (wg,bucket) owns
// a private contiguous sub-region -> L2 merges the 4B writes into full lines.
__global__ __launch_bounds__(256) void k_split(
    const int* __restrict__ epack, const int* __restrict__ off2,
    int* __restrict__ tmp, int E, int nbucket, int chunk) {
  __shared__ int cur[512];
  const int w = blockIdx.x, t = threadIdx.x;
  for (int b = t; b < nbucket; b += 256) cur[b] = off2[b * NB_SPLIT + w];
  __syncthreads();
  const int i0 = w * chunk;
  const int i1 = min(E, i0 + chunk);
  for (int i = i0 + t; i < i1; i += 256) {
    int p = epack[i];
    int b = (int)(((unsigned)p) >> (16 + BUCKET_SHIFT));
    int pos = atomicAdd(&cur[b], 1);
    tmp[pos] = p;
  }
}

// Pass C: one wg per bucket. Counts per-node degree from the bucket's edge
// stream (LDS), scans it (128-wide), writes rowp + dis, then places edges.
__global__ __launch_bounds__(256) void k_csr(
    const int* __restrict__ tmp, const int* __restrict__ off2,
    int* __restrict__ rowp, float* __restrict__ dis, int* __restrict__ col,
    int E, int nbucket, int N) {
  __shared__ int lcnt[128];
  __shared__ int lcur[128];
  __shared__ int wtot;
  const int b = blockIdx.x, t = threadIdx.x;
  const int nb0 = b << BUCKET_SHIFT;
  const int nn = min(1 << BUCKET_SHIFT, N - nb0);
  if (t < 128) lcnt[t] = 0;
  __syncthreads();
  const int s0 = off2[b * NB_SPLIT];
  const int s1 = (b + 1 < nbucket) ? off2[(b + 1) * NB_SPLIT] : E;
  for (int i = s0 + t; i < s1; i += 256) {
    atomicAdd(&lcnt[((unsigned)tmp[i] >> 16) & 127u], 1);
  }
  __syncthreads();
  int v = 0, sc = 0;
  if (t < 128) {
    v = lcnt[t];
    sc = v;
    #pragma unroll
    for (int o = 1; o < 64; o <<= 1) {
      int u = __shfl_up(sc, o);
      if ((t & 63) >= o) sc += u;
    }
    if (t == 63) wtot = sc;          // wave-0 inclusive total
  }
  __syncthreads();
  if (t < 128) {
    int ex = s0 + ((t >= 64) ? wtot : 0) + sc - v;   // exclusive prefix
    lcur[t] = ex;
    if (t < nn) {
      rowp[nb0 + t] = ex;
      dis[nb0 + t] = rsqrtf((float)(v + 1));
    }
  }
  if (t == 0) rowp[nb0 + nn] = s1;   // bucket end (== next bucket's start)
  __syncthreads();
  for (int i = s0 + t; i < s1; i += 256) {
    unsigned p = (unsigned)tmp[i];
    int j = (int)((p >> 16) & ((1u << BUCKET_SHIFT) - 1));
    int pos = atomicAdd(&lcur[j], 1);
    col[pos] = (int)(p & 0xffffu);
  }
}

// 3-dim aggregation.
// PRESCALE=1: out3[i] = dis[i] * (sum_e in3[s]*dis[s] + in3[i]*dis[i])
// PRESCALE=0: out3[i] = bias + dis[i] * (sum_e in3[s] + in3[i])   (in3 pre-scaled)
template <int PRESCALE>
__global__ void k_agg3(const float* __restrict__ in3, float* __restrict__ out3,
                       const int* __restrict__ rowp, const int* __restrict__ col,
                       const float* __restrict__ dis, const float* __restrict__ bias,
                       int n) {
  int i = blockIdx.x * blockDim.x + threadIdx.x;
  if (i >= n) return;
  const float di = dis[i];
  float a0, a1, a2;
  if (PRESCALE) {
    a0 = in3[i * 3 + 0] * di; a1 = in3[i * 3 + 1] * di; a2 = in3[i * 3 + 2] * di;
  } else {
    a0 = in3[i * 3 + 0]; a1 = in3[i * 3 + 1]; a2 = in3[i * 3 + 2];
  }
  const int e0 = rowp[i], e1 = rowp[i + 1];
  for (int e = e0; e < e1; ++e) {
    int s = col[e];
    if (PRESCALE) {
      float ds_ = dis[s];
      a0 += in3[s * 3 + 0] * ds_;
      a1 += in3[s * 3 + 1] * ds_;
      a2 += in3[s * 3 + 2] * ds_;
    } else {
      a0 += in3[s * 3 + 0];
      a1 += in3[s * 3 + 1];
      a2 += in3[s * 3 + 2];
    }
  }
  a0 *= di; a1 *= di; a2 *= di;
  if (!PRESCALE && bias) { a0 += bias[0]; a1 += bias[1]; a2 += bias[2]; }
  out3[i * 3 + 0] = a0;
  out3[i * 3 + 1] = a1;
  out3[i * 3 + 2] = a2;
}

// Layer 0 matmul: xs = silu(y3 @ W0 + b0) * dis, output in blocked layout.
__global__ void k_mm0(const float* __restrict__ y3, const float* __restrict__ W0,
                      const float* __restrict__ b0, const float* __restrict__ dis,
                      float* __restrict__ out, int n, int slStride) {
  int gid = blockIdx.x * blockDim.x + threadIdx.x;
  int node = gid >> 5;
  int c = (gid & 31) << 2;
  if (node >= n) return;
  float v0 = y3[node * 3 + 0], v1 = y3[node * 3 + 1], v2 = y3[node * 3 + 2];
  float4 a  = *reinterpret_cast<const float4*>(b0 + c);
  float4 w0 = *reinterpret_cast<const float4*>(W0 + 0 * 128 + c);
  float4 w1 = *reinterpret_cast<const float4*>(W0 + 1 * 128 + c);
  float4 w2 = *reinterpret_cast<const float4*>(W0 + 2 * 128 + c);
  a.x += v0 * w0.x + v1 * w1.x + v2 * w2.x;
  a.y += v0 * w0.y + v1 * w1.y + v2 * w2.y;
  a.z += v0 * w0.z + v1 * w1.z + v2 * w2.z;
  a.w += v0 * w0.w + v1 * w1.w + v2 * w2.w;
  const float d = dis[node];
  a.x = silu_f(a.x) * d; a.y = silu_f(a.y) * d;
  a.z = silu_f(a.z) * d; a.w = silu_f(a.w) * d;
  *reinterpret_cast<float4*>(out + (size_t)(c >> 4) * slStride +
                             (size_t)node * 16 + (c & 15)) = a;
}

// 128-dim aggregation, column-sliced: blockIdx = nb*8 + s; dispatch round-robin
// puts all of slice s on XCD s, whose 3.2 MB slice is L2-resident.
// Wave = one (node, slice): 16 edges in flight (4 lanes x float4 each),
// butterfly reduce over group bits, lanes 0-3 store the 64 B result.
__global__ __launch_bounds__(1024) void k_agg_slice(
    const float* __restrict__ xs, float* __restrict__ y,
    const int* __restrict__ rowp, const int* __restrict__ col,
    const float* __restrict__ dis, int n, int slStride) {
  const int s = blockIdx.x & 7;
  const int nb = blockIdx.x >> 3;
  const int lane = threadIdx.x & 63;
  const int node = nb * 16 + (threadIdx.x >> 6);
  if (node >= n) return;
  const int g = lane >> 2;           // edge slot 0..15
  const int c4 = (lane & 3) << 2;    // col offset within slice
  const float* __restrict__ xb = xs + (size_t)s * slStride + c4;
  const int e0 = rowp[node], e1 = rowp[node + 1];
  float4 acc = make_float4(0.f, 0.f, 0.f, 0.f);
  for (int e = e0 + g; e < e1; e += 16) {
    int src = col[e];
    float4 v = *reinterpret_cast<const float4*>(xb + (size_t)src * 16);
    acc.x += v.x; acc.y += v.y; acc.z += v.z; acc.w += v.w;
  }
  #pragma unroll
  for (int o = 4; o <= 32; o <<= 1) {
    acc.x += __shfl_xor(acc.x, o);
    acc.y += __shfl_xor(acc.y, o);
    acc.z += __shfl_xor(acc.z, o);
    acc.w += __shfl_xor(acc.w, o);
  }
  if (lane < 4) {
    float4 self = *reinterpret_cast<const float4*>(xb + (size_t)node * 16);
    const float d = dis[node];
    float4 r;
    r.x = (acc.x + self.x) * d;
    r.y = (acc.y + self.y) * d;
    r.z = (acc.z + self.z) * d;
    r.w = (acc.w + self.w) * d;
    *reinterpret_cast<float4*>(y + (size_t)s * slStride + (size_t)node * 16 + c4) = r;
  }
}

// Middle matmul: h = silu(x @ W + b) * dis.  W (64 KB) resident in LDS, staged
// once; main loop has NO barriers and unroll 2 (round-4-proven shape).
// 512 threads, 64-row tile, thread = 4r x 4c. x in blocked layout [8][N][16].
// PROJ=1: also project h @ W4 (128->3) and store only the 3-dim result.
template <int PROJ>
__global__ __launch_bounds__(512) void k_mm_w(
    const float* __restrict__ x, const float* __restrict__ W,
    const float* __restrict__ bias, const float* __restrict__ dis,
    float* __restrict__ out, const float* __restrict__ W4, int n, int slStride) {
  __shared__ float ws[128][128];
  const int t = threadIdx.x;
  #pragma unroll
  for (int it = 0; it < 8; ++it) {
    int i = t + it * 512;            // float4 index over 128x128
    *reinterpret_cast<float4*>(&ws[i >> 5][(i & 31) << 2]) =
        *reinterpret_cast<const float4*>(W + (size_t)i * 4);
  }
  __syncthreads();

  const int tc = (t & 31) << 2;      // 4 cols
  const int tr = (t >> 5) << 2;      // 4 rows within the 64-row tile
  const int row0 = blockIdx.x * 64;

  int rb[4];
  #pragma unroll
  for (int r = 0; r < 4; ++r) {
    rb[r] = min(row0 + tr + r, n - 1) * 16;   // clamped; results discarded
  }

  float4 acc[4];
  #pragma unroll
  for (int r = 0; r < 4; ++r) acc[r] = make_float4(0.f, 0.f, 0.f, 0.f);

  #pragma unroll 2
  for (int kk = 0; kk < 128; kk += 4) {
    const float* __restrict__ xk = x + (size_t)(kk >> 4) * slStride + (kk & 15);
    float4 w0 = *reinterpret_cast<const float4*>(&ws[kk + 0][tc]);
    float4 w1 = *reinterpret_cast<const float4*>(&ws[kk + 1][tc]);
    float4 w2 = *reinterpret_cast<const float4*>(&ws[kk + 2][tc]);
    float4 w3 = *reinterpret_cast<const float4*>(&ws[kk + 3][tc]);
    #pragma unroll
    for (int r = 0; r < 4; ++r) {
      float4 xr = *reinterpret_cast<const float4*>(xk + rb[r]);
      acc[r].x += xr.x * w0.x + xr.y * w1.x + xr.z * w2.x + xr.w * w3.x;
      acc[r].y += xr.x * w0.y + xr.y * w1.y + xr.z * w2.y + xr.w * w3.y;
      acc[r].z += xr.x * w0.z + xr.y * w1.z + xr.z * w2.z + xr.w * w3.z;
      acc[r].w += xr.x * w0.w + xr.y * w1.w + xr.z * w2.w + xr.w * w3.w;
    }
  }

  float4 bb = *reinterpret_cast<const float4*>(bias + tc);
  if (PROJ) {
    float w4r[4][3];
    #pragma unroll
    for (int c = 0; c < 4; ++c) {
      w4r[c][0] = W4[(tc + c) * 3 + 0];
      w4r[c][1] = W4[(tc + c) * 3 + 1];
      w4r[c][2] = W4[(tc + c) * 3 + 2];
    }
    #pragma unroll
    for (int r = 0; r < 4; ++r) {
      int row = row0 + tr + r;
      float d = (row < n) ? dis[row] : 0.0f;
      float4 a = acc[r];
      a.x = silu_f(a.x + bb.x) * d;
      a.y = silu_f(a.y + bb.y) * d;
      a.z = silu_f(a.z + bb.z) * d;
      a.w = silu_f(a.w + bb.w) * d;
      float p0 = a.x * w4r[0][0] + a.y * w4r[1][0] + a.z * w4r[2][0] + a.w * w4r[3][0];
      float p1 = a.x * w4r[0][1] + a.y * w4r[1][1] + a.z * w4r[2][1] + a.w * w4r[3][1];
      float p2 = a.x * w4r[0][2] + a.y * w4r[1][2] + a.z * w4r[2][2] + a.w * w4r[3][2];
      #pragma unroll
      for (int m = 16; m >= 1; m >>= 1) {
        p0 += __shfl_xor(p0, m);
        p1 += __shfl_xor(p1, m);
        p2 += __shfl_xor(p2, m);
      }
      if ((t & 31) == 0 && row < n) {
        out[row * 3 + 0] = p0;
        out[row * 3 + 1] = p1;
        out[row * 3 + 2] = p2;
      }
    }
  } else {
    #pragma unroll
    for (int r = 0; r < 4; ++r) {
      int row = row0 + tr + r;
      if (row < n) {
        float4 a = acc[r];
        float d = dis[row];
        a.x = silu_f(a.x + bb.x) * d;
        a.y = silu_f(a.y + bb.y) * d;
        a.z = silu_f(a.z + bb.z) * d;
        a.w = silu_f(a.w + bb.w) * d;
        *reinterpret_cast<float4*>(out + (size_t)(tc >> 4) * slStride +
                                   (size_t)row * 16 + (tc & 15)) = a;
      }
    }
  }
}

extern "C" void kernel_launch(void* const* d_in, const int* in_sizes, int n_in,
                              void* d_out, int out_size, void* d_ws, size_t ws_size,
                              hipStream_t stream) {
  const float* pos = (const float*)d_in[0];
  const int* e32 = (const int*)d_in[1];
  const float* W[5] = {(const float*)d_in[2], (const float*)d_in[4], (const float*)d_in[6],
                       (const float*)d_in[8], (const float*)d_in[10]};
  const float* B[5] = {(const float*)d_in[3], (const float*)d_in[5], (const float*)d_in[7],
                       (const float*)d_in[9], (const float*)d_in[11]};
  float* out = (float*)d_out;

  const int N = in_sizes[0] / 3;
  const int E = in_sizes[1] / 2;
  const int NBUCKET = (N + (1 << BUCKET_SHIFT) - 1) >> BUCKET_SHIFT;  // 391
  const int M = NBUCKET * NB_SPLIT;
  const int chunk = (E + NB_SPLIT - 1) / NB_SPLIT;
  const int slStride = N * 16;           // floats per 16-col slice

  char* base = (char*)d_ws;
  size_t off = 0;
  auto alloc = [&](size_t bytes) -> void* {
    void* p = base + off;
    off += (bytes + 255) & ~(size_t)255;
    return p;
  };
  float* dis   = (float*)alloc((size_t)N * 4);
  int* rowp    = (int*)alloc((size_t)(N + 1) * 4);
  int* bsum2   = (int*)alloc(128 * 4);
  int* flag    = (int*)alloc(256);
  int* cnt2    = (int*)alloc((size_t)M * 4);
  int* off2    = (int*)alloc((size_t)M * 4);
  int* col     = (int*)alloc((size_t)E * 4);
  float* y3    = (float*)alloc((size_t)N * 3 * 4);
  float* bufA  = (float*)alloc((size_t)N * 128 * 4);
  float* bufB  = (float*)alloc((size_t)N * 128 * 4);
  // epack/tmp only live during CSR build; alias the big activation buffers.
  int* epack = (int*)bufA;
  int* tmp   = (int*)bufB;

  const int nblk2 = (M + 1023) / 1024;   // 98

  // --- CSR build ---
  k_detect<<<1, 256, 0, stream>>>(e32, flag);
  k_prep<<<NB_SPLIT, 256, 0, stream>>>(e32, flag, epack, cnt2, E, NBUCKET, chunk);
  k_scan1<<<nblk2, 256, 0, stream>>>(cnt2, off2, bsum2, M);
  k_scan2<<<1, 64, 0, stream>>>(bsum2, nblk2);
  k_scanadd<<<(M + 255) / 256, 256, 0, stream>>>(off2, bsum2, M);
  k_split<<<NB_SPLIT, 256, 0, stream>>>(epack, off2, tmp, E, NBUCKET, chunk);
  k_csr<<<NBUCKET, 256, 0, stream>>>(tmp, off2, rowp, dis, col, E, NBUCKET, N);

  // --- layer 0: 3-dim aggregate (prescale fused) then 3->128 matmul ---
  k_agg3<1><<<(N + 255) / 256, 256, 0, stream>>>(pos, y3, rowp, col, dis, nullptr, N);
  k_mm0<<<(N * 32 + 255) / 256, 256, 0, stream>>>(y3, W[0], B[0], dis, bufA, N, slStride);

  // --- layers 1..2: sliced aggregate (128) then 128x128 matmul + SiLU + dis ---
  const int agg_grid = ((N + 15) / 16) * 8;
  const int mm_grid = (N + 63) / 64;
  for (int l = 1; l <= 2; ++l) {
    k_agg_slice<<<agg_grid, 1024, 0, stream>>>(bufA, bufB, rowp, col, dis, N, slStride);
    k_mm_w<0><<<mm_grid, 512, 0, stream>>>(bufB, W[l], B[l], dis, bufA, nullptr, N, slStride);
  }

  // --- layer 3: aggregate, matmul fused with layer-4's 128->3 projection ---
  k_agg_slice<<<agg_grid, 1024, 0, stream>>>(bufA, bufB, rowp, col, dis, N, slStride);
  k_mm_w<1><<<mm_grid, 512, 0, stream>>>(bufB, W[3], B[3], dis, y3, W[4], N, slStride);

  // --- layer 4: 3-dim aggregate + bias ---
  k_agg3<0><<<(N + 255) / 256, 256, 0, stream>>>(y3, out, rowp, col, dis, B[4], N);

  (void)n_in; (void)out_size; (void)ws_size;
}

// Round 7
// 381.587 us; speedup vs baseline: 11.9857x; 1.4549x over previous
//
#include <hip/hip_runtime.h>
#include <cstdint>
#include <cstddef>

// ---------------------------------------------------------------------------
// GCN: 5 layers, out = Â (x W) + b per layer, SiLU on layers 0-3.
// Â = D^-1/2 (A + I) D^-1/2 built from edge_index with self-loops.
//  - aggregate in the LOWEST-dim space (linearity): layer 0 aggregates the
//    3-dim input; layer 4's 128->3 matmul is fused into layer 3's GEMM
//    epilogue (PROJ) so layer 4 aggregates 3-dim.
//  - CSR build via LDS-binned multisplit.
//  - 128-dim aggregation: column-blocked layout [8][N][16] + XCD-pinned
//    slices (blockIdx%8 -> XCD): L2-resident gather (round-6: FETCH 228->32MB)
//    AND 8 nodes per wave (round-6 lesson: 1 (node,slice)/wave = 1.3KB useful
//    bytes/wave -> overhead/latency-bound at 123us; pack 10KB/wave instead).
//  - GEMM: W (64 KB) resident in LDS, barrier-free main loop, unroll 2 ONLY
//    (round-5 lesson: full unroll -> scratch spill -> 20x regression).
// ---------------------------------------------------------------------------

#define NB_SPLIT 256          // workgroups in prep/split passes
#define BUCKET_SHIFT 7        // 128 nodes per bucket

static __device__ __forceinline__ float silu_f(float x) {
  return x / (1.0f + __expf(-x));
}

// Detect whether edge_index is stored as int64 (odd int32 words all zero) or
// int32. flag = 1 -> int64 layout, 0 -> int32 layout.
__global__ void k_detect(const int* __restrict__ e32, int* __restrict__ flag) {
  __shared__ int any_nonzero;
  if (threadIdx.x == 0) any_nonzero = 0;
  __syncthreads();
  int v = e32[threadIdx.x * 2 + 1];
  if (v != 0) any_nonzero = 1;
  __syncthreads();
  if (threadIdx.x == 0) *flag = (any_nonzero ? 0 : 1);
}

// Pass A: pack edges to 4B records + per-(bucket, wg) histogram.
__global__ __launch_bounds__(256) void k_prep(
    const int* __restrict__ e32, const int* __restrict__ flag,
    int* __restrict__ epack, int* __restrict__ cnt2,
    int E, int nbucket, int chunk) {
  __shared__ int hist[512];
  const int w = blockIdx.x, t = threadIdx.x;
  for (int b = t; b < nbucket; b += 256) hist[b] = 0;
  __syncthreads();
  const int f = *flag;
  const int i0 = w * chunk;
  const int i1 = min(E, i0 + chunk);
  for (int i = i0 + t; i < i1; i += 256) {
    int s, d;
    if (f) { s = e32[2 * i]; d = e32[2 * E + 2 * i]; }
    else   { s = e32[i];     d = e32[E + i]; }
    epack[i] = s | (d << 16);            // requires N <= 65536 (N = 50000)
    atomicAdd(&hist[d >> BUCKET_SHIFT], 1);
  }
  __syncthreads();
  for (int b = t; b < nbucket; b += 256) cnt2[b * NB_SPLIT + w] = hist[b];
}

// Hierarchical exclusive scan, stage 1: 1024 elems/block (4/thread).
__global__ void k_scan1(const int* __restrict__ cnt, int* __restrict__ outp,
                        int* __restrict__ bsum, int n) {
  __shared__ int wsum[4];
  const int t = threadIdx.x;
  const int base = blockIdx.x * 1024 + t * 4;
  int v0 = 0, v1 = 0, v2 = 0, v3 = 0;
  if (base + 0 < n) v0 = cnt[base + 0];
  if (base + 1 < n) v1 = cnt[base + 1];
  if (base + 2 < n) v2 = cnt[base + 2];
  if (base + 3 < n) v3 = cnt[base + 3];
  const int s = v0 + v1 + v2 + v3;
  int sc = s;
  const int lane = t & 63;
  #pragma unroll
  for (int o = 1; o < 64; o <<= 1) {
    int u = __shfl_up(sc, o);
    if (lane >= o) sc += u;
  }
  const int wid = t >> 6;
  if (lane == 63) wsum[wid] = sc;
  __syncthreads();
  int wbase = 0;
  for (int w = 0; w < wid; ++w) wbase += wsum[w];
  const int ex = wbase + sc - s;
  if (base + 0 < n) outp[base + 0] = ex;
  if (base + 1 < n) outp[base + 1] = ex + v0;
  if (base + 2 < n) outp[base + 2] = ex + v0 + v1;
  if (base + 3 < n) outp[base + 3] = ex + v0 + v1 + v2;
  if (t == 0) bsum[blockIdx.x] = wsum[0] + wsum[1] + wsum[2] + wsum[3];
}

// Stage 2: serial exclusive scan of block sums (small).
__global__ void k_scan2(int* __restrict__ bsum, int nblk) {
  if (threadIdx.x == 0 && blockIdx.x == 0) {
    int acc = 0;
    for (int i = 0; i < nblk; ++i) { int v = bsum[i]; bsum[i] = acc; acc += v; }
  }
}

// Stage 3: add block offsets.
__global__ void k_scanadd(int* __restrict__ arr, const int* __restrict__ bsum, int n) {
  int i = blockIdx.x * blockDim.x + threadIdx.x;
  if (i < n) arr[i] += bsum[i >> 10];
}

// Pass B: scatter packed edges into bucket-grouped tmp; each (wg,bucket) owns
// a private contiguous sub-region -> L2 merges the 4B writes into full lines.
__global__ __launch_bounds__(256) void k_split(
    const int* __restrict__ epack, const int* __restrict__ off2,
    int* __restrict__ tmp, int E, int nbucket, int chunk) {
  __shared__ int cur[512];
  const int w = blockIdx.x, t = threadIdx.x;
  for (int b = t; b < nbucket; b += 256) cur[b] = off2[b * NB_SPLIT + w];
  __syncthreads();
  const int i0 = w * chunk;
  const int i1 = min(E, i0 + chunk);
  for (int i = i0 + t; i < i1; i += 256) {
    int p = epack[i];
    int b = (int)(((unsigned)p) >> (16 + BUCKET_SHIFT));
    int pos = atomicAdd(&cur[b], 1);
    tmp[pos] = p;
  }
}

// Pass C: one wg per bucket. Counts per-node degree from the bucket's edge
// stream (LDS), scans it (128-wide), writes rowp + dis, then places edges.
__global__ __launch_bounds__(256) void k_csr(
    const int* __restrict__ tmp, const int* __restrict__ off2,
    int* __restrict__ rowp, float* __restrict__ dis, int* __restrict__ col,
    int E, int nbucket, int N) {
  __shared__ int lcnt[128];
  __shared__ int lcur[128];
  __shared__ int wtot;
  const int b = blockIdx.x, t = threadIdx.x;
  const int nb0 = b << BUCKET_SHIFT;
  const int nn = min(1 << BUCKET_SHIFT, N - nb0);
  if (t < 128) lcnt[t] = 0;
  __syncthreads();
  const int s0 = off2[b * NB_SPLIT];
  const int s1 = (b + 1 < nbucket) ? off2[(b + 1) * NB_SPLIT] : E;
  for (int i = s0 + t; i < s1; i += 256) {
    atomicAdd(&lcnt[((unsigned)tmp[i] >> 16) & 127u], 1);
  }
  __syncthreads();
  int v = 0, sc = 0;
  if (t < 128) {
    v = lcnt[t];
    sc = v;
    #pragma unroll
    for (int o = 1; o < 64; o <<= 1) {
      int u = __shfl_up(sc, o);
      if ((t & 63) >= o) sc += u;
    }
    if (t == 63) wtot = sc;          // wave-0 inclusive total
  }
  __syncthreads();
  if (t < 128) {
    int ex = s0 + ((t >= 64) ? wtot : 0) + sc - v;   // exclusive prefix
    lcur[t] = ex;
    if (t < nn) {
      rowp[nb0 + t] = ex;
      dis[nb0 + t] = rsqrtf((float)(v + 1));
    }
  }
  if (t == 0) rowp[nb0 + nn] = s1;   // bucket end (== next bucket's start)
  __syncthreads();
  for (int i = s0 + t; i < s1; i += 256) {
    unsigned p = (unsigned)tmp[i];
    int j = (int)((p >> 16) & ((1u << BUCKET_SHIFT) - 1));
    int pos = atomicAdd(&lcur[j], 1);
    col[pos] = (int)(p & 0xffffu);
  }
}

// 3-dim aggregation.
// PRESCALE=1: out3[i] = dis[i] * (sum_e in3[s]*dis[s] + in3[i]*dis[i])
// PRESCALE=0: out3[i] = bias + dis[i] * (sum_e in3[s] + in3[i])   (in3 pre-scaled)
template <int PRESCALE>
__global__ void k_agg3(const float* __restrict__ in3, float* __restrict__ out3,
                       const int* __restrict__ rowp, const int* __restrict__ col,
                       const float* __restrict__ dis, const float* __restrict__ bias,
                       int n) {
  int i = blockIdx.x * blockDim.x + threadIdx.x;
  if (i >= n) return;
  const float di = dis[i];
  float a0, a1, a2;
  if (PRESCALE) {
    a0 = in3[i * 3 + 0] * di; a1 = in3[i * 3 + 1] * di; a2 = in3[i * 3 + 2] * di;
  } else {
    a0 = in3[i * 3 + 0]; a1 = in3[i * 3 + 1]; a2 = in3[i * 3 + 2];
  }
  const int e0 = rowp[i], e1 = rowp[i + 1];
  for (int e = e0; e < e1; ++e) {
    int s = col[e];
    if (PRESCALE) {
      float ds_ = dis[s];
      a0 += in3[s * 3 + 0] * ds_;
      a1 += in3[s * 3 + 1] * ds_;
      a2 += in3[s * 3 + 2] * ds_;
    } else {
      a0 += in3[s * 3 + 0];
      a1 += in3[s * 3 + 1];
      a2 += in3[s * 3 + 2];
    }
  }
  a0 *= di; a1 *= di; a2 *= di;
  if (!PRESCALE && bias) { a0 += bias[0]; a1 += bias[1]; a2 += bias[2]; }
  out3[i * 3 + 0] = a0;
  out3[i * 3 + 1] = a1;
  out3[i * 3 + 2] = a2;
}

// Layer 0 matmul: xs = silu(y3 @ W0 + b0) * dis, output in blocked layout.
__global__ void k_mm0(const float* __restrict__ y3, const float* __restrict__ W0,
                      const float* __restrict__ b0, const float* __restrict__ dis,
                      float* __restrict__ out, int n, int slStride) {
  int gid = blockIdx.x * blockDim.x + threadIdx.x;
  int node = gid >> 5;
  int c = (gid & 31) << 2;
  if (node >= n) return;
  float v0 = y3[node * 3 + 0], v1 = y3[node * 3 + 1], v2 = y3[node * 3 + 2];
  float4 a  = *reinterpret_cast<const float4*>(b0 + c);
  float4 w0 = *reinterpret_cast<const float4*>(W0 + 0 * 128 + c);
  float4 w1 = *reinterpret_cast<const float4*>(W0 + 1 * 128 + c);
  float4 w2 = *reinterpret_cast<const float4*>(W0 + 2 * 128 + c);
  a.x += v0 * w0.x + v1 * w1.x + v2 * w2.x;
  a.y += v0 * w0.y + v1 * w1.y + v2 * w2.y;
  a.z += v0 * w0.z + v1 * w1.z + v2 * w2.z;
  a.w += v0 * w0.w + v1 * w1.w + v2 * w2.w;
  const float d = dis[node];
  a.x = silu_f(a.x) * d; a.y = silu_f(a.y) * d;
  a.z = silu_f(a.z) * d; a.w = silu_f(a.w) * d;
  *reinterpret_cast<float4*>(out + (size_t)(c >> 4) * slStride +
                             (size_t)node * 16 + (c & 15)) = a;
}

// 128-dim aggregation, column-sliced + XCD-pinned (blockIdx&7 -> slice -> XCD).
// 8 nodes per wave: lane = nsub(3b) | ch(1b) | c4(2b); each node has 2 edge
// channels x 4 lanes x float4 (one 64 B slice row per edge), channels pair-
// unrolled -> ~16 gather segments in flight per wave, ~10 KB useful bytes/wave.
__global__ __launch_bounds__(256) void k_agg_slice(
    const float* __restrict__ xs, float* __restrict__ y,
    const int* __restrict__ rowp, const int* __restrict__ col,
    const float* __restrict__ dis, int n, int slStride) {
  const int s = blockIdx.x & 7;
  const int nb = blockIdx.x >> 3;          // 32-node group
  const int t = threadIdx.x;
  const int lane = t & 63;
  const int nsub = lane >> 3;              // node within this wave's 8
  const int ch = (lane >> 2) & 1;          // edge channel 0/1
  const int c4 = (lane & 3) << 2;          // float offset within 16-col slice
  const int node = nb * 32 + (t >> 6) * 8 + nsub;
  const bool valid = node < n;
  int e0 = 0, e1 = 0;
  if (valid) { e0 = rowp[node]; e1 = rowp[node + 1]; }
  const float* __restrict__ xb = xs + (size_t)s * slStride + c4;

  float4 acc0 = make_float4(0.f, 0.f, 0.f, 0.f);
  float4 acc1 = make_float4(0.f, 0.f, 0.f, 0.f);
  int e = e0 + ch;
  for (; e + 2 < e1; e += 4) {             // 2 edges per channel per iter
    int s0 = col[e], s1 = col[e + 2];
    float4 v0 = *reinterpret_cast<const float4*>(xb + (size_t)s0 * 16);
    float4 v1 = *reinterpret_cast<const float4*>(xb + (size_t)s1 * 16);
    acc0.x += v0.x; acc0.y += v0.y; acc0.z += v0.z; acc0.w += v0.w;
    acc1.x += v1.x; acc1.y += v1.y; acc1.z += v1.z; acc1.w += v1.w;
  }
  if (e < e1) {
    int s0 = col[e];
    float4 v0 = *reinterpret_cast<const float4*>(xb + (size_t)s0 * 16);
    acc0.x += v0.x; acc0.y += v0.y; acc0.z += v0.z; acc0.w += v0.w;
  }
  acc0.x += acc1.x; acc0.y += acc1.y; acc0.z += acc1.z; acc0.w += acc1.w;
  // combine the two channels (lane bit 2)
  acc0.x += __shfl_xor(acc0.x, 4);
  acc0.y += __shfl_xor(acc0.y, 4);
  acc0.z += __shfl_xor(acc0.z, 4);
  acc0.w += __shfl_xor(acc0.w, 4);
  if (valid && ch == 0) {
    float4 self = *reinterpret_cast<const float4*>(xb + (size_t)node * 16);
    const float d = dis[node];
    float4 r;
    r.x = (acc0.x + self.x) * d;
    r.y = (acc0.y + self.y) * d;
    r.z = (acc0.z + self.z) * d;
    r.w = (acc0.w + self.w) * d;
    *reinterpret_cast<float4*>(y + (size_t)s * slStride + (size_t)node * 16 + c4) = r;
  }
}

// Middle matmul: h = silu(x @ W + b) * dis.  W (64 KB) resident in LDS, staged
// once; main loop has NO barriers and unroll 2 (round-4-proven shape).
// 512 threads, 64-row tile, thread = 4r x 4c. x in blocked layout [8][N][16].
// PROJ=1: also project h @ W4 (128->3) and store only the 3-dim result.
template <int PROJ>
__global__ __launch_bounds__(512) void k_mm_w(
    const float* __restrict__ x, const float* __restrict__ W,
    const float* __restrict__ bias, const float* __restrict__ dis,
    float* __restrict__ out, const float* __restrict__ W4, int n, int slStride) {
  __shared__ float ws[128][128];
  const int t = threadIdx.x;
  #pragma unroll
  for (int it = 0; it < 8; ++it) {
    int i = t + it * 512;            // float4 index over 128x128
    *reinterpret_cast<float4*>(&ws[i >> 5][(i & 31) << 2]) =
        *reinterpret_cast<const float4*>(W + (size_t)i * 4);
  }
  __syncthreads();

  const int tc = (t & 31) << 2;      // 4 cols
  const int tr = (t >> 5) << 2;      // 4 rows within the 64-row tile
  const int row0 = blockIdx.x * 64;

  int rb[4];
  #pragma unroll
  for (int r = 0; r < 4; ++r) {
    rb[r] = min(row0 + tr + r, n - 1) * 16;   // clamped; results discarded
  }

  float4 acc[4];
  #pragma unroll
  for (int r = 0; r < 4; ++r) acc[r] = make_float4(0.f, 0.f, 0.f, 0.f);

  #pragma unroll 2
  for (int kk = 0; kk < 128; kk += 4) {
    const float* __restrict__ xk = x + (size_t)(kk >> 4) * slStride + (kk & 15);
    float4 w0 = *reinterpret_cast<const float4*>(&ws[kk + 0][tc]);
    float4 w1 = *reinterpret_cast<const float4*>(&ws[kk + 1][tc]);
    float4 w2 = *reinterpret_cast<const float4*>(&ws[kk + 2][tc]);
    float4 w3 = *reinterpret_cast<const float4*>(&ws[kk + 3][tc]);
    #pragma unroll
    for (int r = 0; r < 4; ++r) {
      float4 xr = *reinterpret_cast<const float4*>(xk + rb[r]);
      acc[r].x += xr.x * w0.x + xr.y * w1.x + xr.z * w2.x + xr.w * w3.x;
      acc[r].y += xr.x * w0.y + xr.y * w1.y + xr.z * w2.y + xr.w * w3.y;
      acc[r].z += xr.x * w0.z + xr.y * w1.z + xr.z * w2.z + xr.w * w3.z;
      acc[r].w += xr.x * w0.w + xr.y * w1.w + xr.z * w2.w + xr.w * w3.w;
    }
  }

  float4 bb = *reinterpret_cast<const float4*>(bias + tc);
  if (PROJ) {
    float w4r[4][3];
    #pragma unroll
    for (int c = 0; c < 4; ++c) {
      w4r[c][0] = W4[(tc + c) * 3 + 0];
      w4r[c][1] = W4[(tc + c) * 3 + 1];
      w4r[c][2] = W4[(tc + c) * 3 + 2];
    }
    #pragma unroll
    for (int r = 0; r < 4; ++r) {
      int row = row0 + tr + r;
      float d = (row < n) ? dis[row] : 0.0f;
      float4 a = acc[r];
      a.x = silu_f(a.x + bb.x) * d;
      a.y = silu_f(a.y + bb.y) * d;
      a.z = silu_f(a.z + bb.z) * d;
      a.w = silu_f(a.w + bb.w) * d;
      float p0 = a.x * w4r[0][0] + a.y * w4r[1][0] + a.z * w4r[2][0] + a.w * w4r[3][0];
      float p1 = a.x * w4r[0][1] + a.y * w4r[1][1] + a.z * w4r[2][1] + a.w * w4r[3][1];
      float p2 = a.x * w4r[0][2] + a.y * w4r[1][2] + a.z * w4r[2][2] + a.w * w4r[3][2];
      #pragma unroll
      for (int m = 16; m >= 1; m >>= 1) {
        p0 += __shfl_xor(p0, m);
        p1 += __shfl_xor(p1, m);
        p2 += __shfl_xor(p2, m);
      }
      if ((t & 31) == 0 && row < n) {
        out[row * 3 + 0] = p0;
        out[row * 3 + 1] = p1;
        out[row * 3 + 2] = p2;
      }
    }
  } else {
    #pragma unroll
    for (int r = 0; r < 4; ++r) {
      int row = row0 + tr + r;
      if (row < n) {
        float4 a = acc[r];
        float d = dis[row];
        a.x = silu_f(a.x + bb.x) * d;
        a.y = silu_f(a.y + bb.y) * d;
        a.z = silu_f(a.z + bb.z) * d;
        a.w = silu_f(a.w + bb.w) * d;
        *reinterpret_cast<float4*>(out + (size_t)(tc >> 4) * slStride +
                                   (size_t)row * 16 + (tc & 15)) = a;
      }
    }
  }
}

extern "C" void kernel_launch(void* const* d_in, const int* in_sizes, int n_in,
                              void* d_out, int out_size, void* d_ws, size_t ws_size,
                              hipStream_t stream) {
  const float* pos = (const float*)d_in[0];
  const int* e32 = (const int*)d_in[1];
  const float* W[5] = {(const float*)d_in[2], (const float*)d_in[4], (const float*)d_in[6],
                       (const float*)d_in[8], (const float*)d_in[10]};
  const float* B[5] = {(const float*)d_in[3], (const float*)d_in[5], (const float*)d_in[7],
                       (const float*)d_in[9], (const float*)d_in[11]};
  float* out = (float*)d_out;

  const int N = in_sizes[0] / 3;
  const int E = in_sizes[1] / 2;
  const int NBUCKET = (N + (1 << BUCKET_SHIFT) - 1) >> BUCKET_SHIFT;  // 391
  const int M = NBUCKET * NB_SPLIT;
  const int chunk = (E + NB_SPLIT - 1) / NB_SPLIT;
  const int slStride = N * 16;           // floats per 16-col slice

  char* base = (char*)d_ws;
  size_t off = 0;
  auto alloc = [&](size_t bytes) -> void* {
    void* p = base + off;
    off += (bytes + 255) & ~(size_t)255;
    return p;
  };
  float* dis   = (float*)alloc((size_t)N * 4);
  int* rowp    = (int*)alloc((size_t)(N + 1) * 4);
  int* bsum2   = (int*)alloc(128 * 4);
  int* flag    = (int*)alloc(256);
  int* cnt2    = (int*)alloc((size_t)M * 4);
  int* off2    = (int*)alloc((size_t)M * 4);
  int* col     = (int*)alloc((size_t)E * 4);
  float* y3    = (float*)alloc((size_t)N * 3 * 4);
  float* bufA  = (float*)alloc((size_t)N * 128 * 4);
  float* bufB  = (float*)alloc((size_t)N * 128 * 4);
  // epack/tmp only live during CSR build; alias the big activation buffers.
  int* epack = (int*)bufA;
  int* tmp   = (int*)bufB;

  const int nblk2 = (M + 1023) / 1024;   // 98

  // --- CSR build ---
  k_detect<<<1, 256, 0, stream>>>(e32, flag);
  k_prep<<<NB_SPLIT, 256, 0, stream>>>(e32, flag, epack, cnt2, E, NBUCKET, chunk);
  k_scan1<<<nblk2, 256, 0, stream>>>(cnt2, off2, bsum2, M);
  k_scan2<<<1, 64, 0, stream>>>(bsum2, nblk2);
  k_scanadd<<<(M + 255) / 256, 256, 0, stream>>>(off2, bsum2, M);
  k_split<<<NB_SPLIT, 256, 0, stream>>>(epack, off2, tmp, E, NBUCKET, chunk);
  k_csr<<<NBUCKET, 256, 0, stream>>>(tmp, off2, rowp, dis, col, E, NBUCKET, N);

  // --- layer 0: 3-dim aggregate (prescale fused) then 3->128 matmul ---
  k_agg3<1><<<(N + 255) / 256, 256, 0, stream>>>(pos, y3, rowp, col, dis, nullptr, N);
  k_mm0<<<(N * 32 + 255) / 256, 256, 0, stream>>>(y3, W[0], B[0], dis, bufA, N, slStride);

  // --- layers 1..2: sliced aggregate (128) then 128x128 matmul + SiLU + dis ---
  const int agg_grid = ((N + 31) / 32) * 8;
  const int mm_grid = (N + 63) / 64;
  for (int l = 1; l <= 2; ++l) {
    k_agg_slice<<<agg_grid, 256, 0, stream>>>(bufA, bufB, rowp, col, dis, N, slStride);
    k_mm_w<0><<<mm_grid, 512, 0, stream>>>(bufB, W[l], B[l], dis, bufA, nullptr, N, slStride);
  }

  // --- layer 3: aggregate, matmul fused with layer-4's 128->3 projection ---
  k_agg_slice<<<agg_grid, 256, 0, stream>>>(bufA, bufB, rowp, col, dis, N, slStride);
  k_mm_w<1><<<mm_grid, 512, 0, stream>>>(bufB, W[3], B[3], dis, y3, W[4], N, slStride);

  // --- layer 4: 3-dim aggregate + bias ---
  k_agg3<0><<<(N + 255) / 256, 256, 0, stream>>>(y3, out, rowp, col, dis, B[4], N);

  (void)n_in; (void)out_size; (void)ws_size;
}

// Round 8
// 354.536 us; speedup vs baseline: 12.9002x; 1.0763x over previous
//
#include <hip/hip_runtime.h>
#include <cstdint>
#include <cstddef>

// ---------------------------------------------------------------------------
// GCN: 5 layers, out = Â (x W) + b per layer, SiLU on layers 0-3.
// Â = D^-1/2 (A + I) D^-1/2 built from edge_index with self-loops.
//  - aggregate in the LOWEST-dim space (linearity): layer 0 aggregates the
//    3-dim input; layer 4's 128->3 matmul is fused into layer 3's GEMM
//    epilogue (PROJ) so layer 4 aggregates 3-dim.
//  - CSR build via LDS-binned multisplit; col stored as ushort (N < 65536).
//  - 128-dim aggregation: column-blocked layout [8][N][16] + XCD-pinned
//    slices (blockIdx&7 -> XCD): L2-resident gather (round-6: FETCH 228->32MB),
//    8 nodes/wave (round-7: 123->59us), 4-deep gather chains per lane
//    (round-7 lesson: 2 chains -> ~2.8KB in flight/CU -> latency-bound 24% VALU).
//  - GEMM: W (64 KB) resident in LDS, barrier-free main loop, unroll 2 ONLY
//    (round-5 lesson: full unroll -> scratch spill -> 20x regression).
// ---------------------------------------------------------------------------

#define NB_SPLIT 256          // workgroups in prep/split passes
#define BUCKET_SHIFT 7        // 128 nodes per bucket

static __device__ __forceinline__ float silu_f(float x) {
  return x / (1.0f + __expf(-x));
}

// Detect whether edge_index is stored as int64 (odd int32 words all zero) or
// int32. flag = 1 -> int64 layout, 0 -> int32 layout.
__global__ void k_detect(const int* __restrict__ e32, int* __restrict__ flag) {
  __shared__ int any_nonzero;
  if (threadIdx.x == 0) any_nonzero = 0;
  __syncthreads();
  int v = e32[threadIdx.x * 2 + 1];
  if (v != 0) any_nonzero = 1;
  __syncthreads();
  if (threadIdx.x == 0) *flag = (any_nonzero ? 0 : 1);
}

// Pass A: pack edges to 4B records + per-(bucket, wg) histogram.
__global__ __launch_bounds__(256) void k_prep(
    const int* __restrict__ e32, const int* __restrict__ flag,
    int* __restrict__ epack, int* __restrict__ cnt2,
    int E, int nbucket, int chunk) {
  __shared__ int hist[512];
  const int w = blockIdx.x, t = threadIdx.x;
  for (int b = t; b < nbucket; b += 256) hist[b] = 0;
  __syncthreads();
  const int f = *flag;
  const int i0 = w * chunk;
  const int i1 = min(E, i0 + chunk);
  for (int i = i0 + t; i < i1; i += 256) {
    int s, d;
    if (f) { s = e32[2 * i]; d = e32[2 * E + 2 * i]; }
    else   { s = e32[i];     d = e32[E + i]; }
    epack[i] = s | (d << 16);            // requires N <= 65536 (N = 50000)
    atomicAdd(&hist[d >> BUCKET_SHIFT], 1);
  }
  __syncthreads();
  for (int b = t; b < nbucket; b += 256) cnt2[b * NB_SPLIT + w] = hist[b];
}

// Hierarchical exclusive scan, stage 1: 1024 elems/block (4/thread).
__global__ void k_scan1(const int* __restrict__ cnt, int* __restrict__ outp,
                        int* __restrict__ bsum, int n) {
  __shared__ int wsum[4];
  const int t = threadIdx.x;
  const int base = blockIdx.x * 1024 + t * 4;
  int v0 = 0, v1 = 0, v2 = 0, v3 = 0;
  if (base + 0 < n) v0 = cnt[base + 0];
  if (base + 1 < n) v1 = cnt[base + 1];
  if (base + 2 < n) v2 = cnt[base + 2];
  if (base + 3 < n) v3 = cnt[base + 3];
  const int s = v0 + v1 + v2 + v3;
  int sc = s;
  const int lane = t & 63;
  #pragma unroll
  for (int o = 1; o < 64; o <<= 1) {
    int u = __shfl_up(sc, o);
    if (lane >= o) sc += u;
  }
  const int wid = t >> 6;
  if (lane == 63) wsum[wid] = sc;
  __syncthreads();
  int wbase = 0;
  for (int w = 0; w < wid; ++w) wbase += wsum[w];
  const int ex = wbase + sc - s;
  if (base + 0 < n) outp[base + 0] = ex;
  if (base + 1 < n) outp[base + 1] = ex + v0;
  if (base + 2 < n) outp[base + 2] = ex + v0 + v1;
  if (base + 3 < n) outp[base + 3] = ex + v0 + v1 + v2;
  if (t == 0) bsum[blockIdx.x] = wsum[0] + wsum[1] + wsum[2] + wsum[3];
}

// Stage 2: serial exclusive scan of block sums (small).
__global__ void k_scan2(int* __restrict__ bsum, int nblk) {
  if (threadIdx.x == 0 && blockIdx.x == 0) {
    int acc = 0;
    for (int i = 0; i < nblk; ++i) { int v = bsum[i]; bsum[i] = acc; acc += v; }
  }
}

// Stage 3: add block offsets.
__global__ void k_scanadd(int* __restrict__ arr, const int* __restrict__ bsum, int n) {
  int i = blockIdx.x * blockDim.x + threadIdx.x;
  if (i < n) arr[i] += bsum[i >> 10];
}

// Pass B: scatter packed edges into bucket-grouped tmp; each (wg,bucket) owns
// a private contiguous sub-region -> L2 merges the 4B writes into full lines.
__global__ __launch_bounds__(256) void k_split(
    const int* __restrict__ epack, const int* __restrict__ off2,
    int* __restrict__ tmp, int E, int nbucket, int chunk) {
  __shared__ int cur[512];
  const int w = blockIdx.x, t = threadIdx.x;
  for (int b = t; b < nbucket; b += 256) cur[b] = off2[b * NB_SPLIT + w];
  __syncthreads();
  const int i0 = w * chunk;
  const int i1 = min(E, i0 + chunk);
  for (int i = i0 + t; i < i1; i += 256) {
    int p = epack[i];
    int b = (int)(((unsigned)p) >> (16 + BUCKET_SHIFT));
    int pos = atomicAdd(&cur[b], 1);
    tmp[pos] = p;
  }
}

// Pass C: one wg per bucket. Counts per-node degree from the bucket's edge
// stream (LDS), scans it (128-wide), writes rowp + dis, then places edges
// (col as ushort: halves the per-slice edge-stream re-read in aggregation).
__global__ __launch_bounds__(256) void k_csr(
    const int* __restrict__ tmp, const int* __restrict__ off2,
    int* __restrict__ rowp, float* __restrict__ dis,
    unsigned short* __restrict__ col,
    int E, int nbucket, int N) {
  __shared__ int lcnt[128];
  __shared__ int lcur[128];
  __shared__ int wtot;
  const int b = blockIdx.x, t = threadIdx.x;
  const int nb0 = b << BUCKET_SHIFT;
  const int nn = min(1 << BUCKET_SHIFT, N - nb0);
  if (t < 128) lcnt[t] = 0;
  __syncthreads();
  const int s0 = off2[b * NB_SPLIT];
  const int s1 = (b + 1 < nbucket) ? off2[(b + 1) * NB_SPLIT] : E;
  for (int i = s0 + t; i < s1; i += 256) {
    atomicAdd(&lcnt[((unsigned)tmp[i] >> 16) & 127u], 1);
  }
  __syncthreads();
  int v = 0, sc = 0;
  if (t < 128) {
    v = lcnt[t];
    sc = v;
    #pragma unroll
    for (int o = 1; o < 64; o <<= 1) {
      int u = __shfl_up(sc, o);
      if ((t & 63) >= o) sc += u;
    }
    if (t == 63) wtot = sc;          // wave-0 inclusive total
  }
  __syncthreads();
  if (t < 128) {
    int ex = s0 + ((t >= 64) ? wtot : 0) + sc - v;   // exclusive prefix
    lcur[t] = ex;
    if (t < nn) {
      rowp[nb0 + t] = ex;
      dis[nb0 + t] = rsqrtf((float)(v + 1));
    }
  }
  if (t == 0) rowp[nb0 + nn] = s1;   // bucket end (== next bucket's start)
  __syncthreads();
  for (int i = s0 + t; i < s1; i += 256) {
    unsigned p = (unsigned)tmp[i];
    int j = (int)((p >> 16) & ((1u << BUCKET_SHIFT) - 1));
    int pos = atomicAdd(&lcur[j], 1);
    col[pos] = (unsigned short)(p & 0xffffu);
  }
}

// 3-dim aggregation.
// PRESCALE=1: out3[i] = dis[i] * (sum_e in3[s]*dis[s] + in3[i]*dis[i])
// PRESCALE=0: out3[i] = bias + dis[i] * (sum_e in3[s] + in3[i])   (in3 pre-scaled)
template <int PRESCALE>
__global__ void k_agg3(const float* __restrict__ in3, float* __restrict__ out3,
                       const int* __restrict__ rowp,
                       const unsigned short* __restrict__ col,
                       const float* __restrict__ dis, const float* __restrict__ bias,
                       int n) {
  int i = blockIdx.x * blockDim.x + threadIdx.x;
  if (i >= n) return;
  const float di = dis[i];
  float a0, a1, a2;
  if (PRESCALE) {
    a0 = in3[i * 3 + 0] * di; a1 = in3[i * 3 + 1] * di; a2 = in3[i * 3 + 2] * di;
  } else {
    a0 = in3[i * 3 + 0]; a1 = in3[i * 3 + 1]; a2 = in3[i * 3 + 2];
  }
  const int e0 = rowp[i], e1 = rowp[i + 1];
  for (int e = e0; e < e1; ++e) {
    int s = col[e];
    if (PRESCALE) {
      float ds_ = dis[s];
      a0 += in3[s * 3 + 0] * ds_;
      a1 += in3[s * 3 + 1] * ds_;
      a2 += in3[s * 3 + 2] * ds_;
    } else {
      a0 += in3[s * 3 + 0];
      a1 += in3[s * 3 + 1];
      a2 += in3[s * 3 + 2];
    }
  }
  a0 *= di; a1 *= di; a2 *= di;
  if (!PRESCALE && bias) { a0 += bias[0]; a1 += bias[1]; a2 += bias[2]; }
  out3[i * 3 + 0] = a0;
  out3[i * 3 + 1] = a1;
  out3[i * 3 + 2] = a2;
}

// Layer 0 matmul: xs = silu(y3 @ W0 + b0) * dis, output in blocked layout.
__global__ void k_mm0(const float* __restrict__ y3, const float* __restrict__ W0,
                      const float* __restrict__ b0, const float* __restrict__ dis,
                      float* __restrict__ out, int n, int slStride) {
  int gid = blockIdx.x * blockDim.x + threadIdx.x;
  int node = gid >> 5;
  int c = (gid & 31) << 2;
  if (node >= n) return;
  float v0 = y3[node * 3 + 0], v1 = y3[node * 3 + 1], v2 = y3[node * 3 + 2];
  float4 a  = *reinterpret_cast<const float4*>(b0 + c);
  float4 w0 = *reinterpret_cast<const float4*>(W0 + 0 * 128 + c);
  float4 w1 = *reinterpret_cast<const float4*>(W0 + 1 * 128 + c);
  float4 w2 = *reinterpret_cast<const float4*>(W0 + 2 * 128 + c);
  a.x += v0 * w0.x + v1 * w1.x + v2 * w2.x;
  a.y += v0 * w0.y + v1 * w1.y + v2 * w2.y;
  a.z += v0 * w0.z + v1 * w1.z + v2 * w2.z;
  a.w += v0 * w0.w + v1 * w1.w + v2 * w2.w;
  const float d = dis[node];
  a.x = silu_f(a.x) * d; a.y = silu_f(a.y) * d;
  a.z = silu_f(a.z) * d; a.w = silu_f(a.w) * d;
  *reinterpret_cast<float4*>(out + (size_t)(c >> 4) * slStride +
                             (size_t)node * 16 + (c & 15)) = a;
}

// 128-dim aggregation, column-sliced + XCD-pinned (blockIdx&7 -> slice -> XCD).
// 8 nodes per wave: lane = nsub(3b) | ch(1b) | c4(2b); each node has 2 edge
// channels; each channel keeps FOUR independent gather chains in flight
// (round-8: Little's-law fix for the 24%-VALU latency bind).
__global__ __launch_bounds__(256) void k_agg_slice(
    const float* __restrict__ xs, float* __restrict__ y,
    const int* __restrict__ rowp, const unsigned short* __restrict__ col,
    const float* __restrict__ dis, int n, int slStride) {
  const int s = blockIdx.x & 7;
  const int nb = blockIdx.x >> 3;          // 32-node group
  const int t = threadIdx.x;
  const int lane = t & 63;
  const int nsub = lane >> 3;              // node within this wave's 8
  const int ch = (lane >> 2) & 1;          // edge channel 0/1
  const int c4 = (lane & 3) << 2;          // float offset within 16-col slice
  const int node = nb * 32 + (t >> 6) * 8 + nsub;
  const bool valid = node < n;
  int e0 = 0, e1 = 0;
  if (valid) { e0 = rowp[node]; e1 = rowp[node + 1]; }
  const float* __restrict__ xb = xs + (size_t)s * slStride + c4;

  float4 a0 = make_float4(0.f, 0.f, 0.f, 0.f);
  float4 a1 = make_float4(0.f, 0.f, 0.f, 0.f);
  float4 a2 = make_float4(0.f, 0.f, 0.f, 0.f);
  float4 a3 = make_float4(0.f, 0.f, 0.f, 0.f);
  int e = e0 + ch;
  // 4 edges per channel per iteration -> 4 independent gather chains in flight
  for (; e + 6 < e1; e += 8) {
    int s0 = col[e], s1 = col[e + 2], s2 = col[e + 4], s3 = col[e + 6];
    float4 v0 = *reinterpret_cast<const float4*>(xb + (size_t)s0 * 16);
    float4 v1 = *reinterpret_cast<const float4*>(xb + (size_t)s1 * 16);
    float4 v2 = *reinterpret_cast<const float4*>(xb + (size_t)s2 * 16);
    float4 v3 = *reinterpret_cast<const float4*>(xb + (size_t)s3 * 16);
    a0.x += v0.x; a0.y += v0.y; a0.z += v0.z; a0.w += v0.w;
    a1.x += v1.x; a1.y += v1.y; a1.z += v1.z; a1.w += v1.w;
    a2.x += v2.x; a2.y += v2.y; a2.z += v2.z; a2.w += v2.w;
    a3.x += v3.x; a3.y += v3.y; a3.z += v3.z; a3.w += v3.w;
  }
  for (; e < e1; e += 2) {
    int s0 = col[e];
    float4 v0 = *reinterpret_cast<const float4*>(xb + (size_t)s0 * 16);
    a0.x += v0.x; a0.y += v0.y; a0.z += v0.z; a0.w += v0.w;
  }
  a0.x += a1.x + a2.x + a3.x;
  a0.y += a1.y + a2.y + a3.y;
  a0.z += a1.z + a2.z + a3.z;
  a0.w += a1.w + a2.w + a3.w;
  // combine the two channels (lane bit 2)
  a0.x += __shfl_xor(a0.x, 4);
  a0.y += __shfl_xor(a0.y, 4);
  a0.z += __shfl_xor(a0.z, 4);
  a0.w += __shfl_xor(a0.w, 4);
  if (valid && ch == 0) {
    float4 self = *reinterpret_cast<const float4*>(xb + (size_t)node * 16);
    const float d = dis[node];
    float4 r;
    r.x = (a0.x + self.x) * d;
    r.y = (a0.y + self.y) * d;
    r.z = (a0.z + self.z) * d;
    r.w = (a0.w + self.w) * d;
    *reinterpret_cast<float4*>(y + (size_t)s * slStride + (size_t)node * 16 + c4) = r;
  }
}

// Middle matmul: h = silu(x @ W + b) * dis.  W (64 KB) resident in LDS, staged
// once; main loop has NO barriers and unroll 2 (round-4-proven shape).
// 512 threads, 64-row tile, thread = 4r x 4c. x in blocked layout [8][N][16].
// PROJ=1: also project h @ W4 (128->3) and store only the 3-dim result.
template <int PROJ>
__global__ __launch_bounds__(512) void k_mm_w(
    const float* __restrict__ x, const float* __restrict__ W,
    const float* __restrict__ bias, const float* __restrict__ dis,
    float* __restrict__ out, const float* __restrict__ W4, int n, int slStride) {
  __shared__ float ws[128][128];
  const int t = threadIdx.x;
  #pragma unroll
  for (int it = 0; it < 8; ++it) {
    int i = t + it * 512;            // float4 index over 128x128
    *reinterpret_cast<float4*>(&ws[i >> 5][(i & 31) << 2]) =
        *reinterpret_cast<const float4*>(W + (size_t)i * 4);
  }
  __syncthreads();

  const int tc = (t & 31) << 2;      // 4 cols
  const int tr = (t >> 5) << 2;      // 4 rows within the 64-row tile
  const int row0 = blockIdx.x * 64;

  int rb[4];
  #pragma unroll
  for (int r = 0; r < 4; ++r) {
    rb[r] = min(row0 + tr + r, n - 1) * 16;   // clamped; results discarded
  }

  float4 acc[4];
  #pragma unroll
  for (int r = 0; r < 4; ++r) acc[r] = make_float4(0.f, 0.f, 0.f, 0.f);

  #pragma unroll 2
  for (int kk = 0; kk < 128; kk += 4) {
    const float* __restrict__ xk = x + (size_t)(kk >> 4) * slStride + (kk & 15);
    float4 w0 = *reinterpret_cast<const float4*>(&ws[kk + 0][tc]);
    float4 w1 = *reinterpret_cast<const float4*>(&ws[kk + 1][tc]);
    float4 w2 = *reinterpret_cast<const float4*>(&ws[kk + 2][tc]);
    float4 w3 = *reinterpret_cast<const float4*>(&ws[kk + 3][tc]);
    #pragma unroll
    for (int r = 0; r < 4; ++r) {
      float4 xr = *reinterpret_cast<const float4*>(xk + rb[r]);
      acc[r].x += xr.x * w0.x + xr.y * w1.x + xr.z * w2.x + xr.w * w3.x;
      acc[r].y += xr.x * w0.y + xr.y * w1.y + xr.z * w2.y + xr.w * w3.y;
      acc[r].z += xr.x * w0.z + xr.y * w1.z + xr.z * w2.z + xr.w * w3.z;
      acc[r].w += xr.x * w0.w + xr.y * w1.w + xr.z * w2.w + xr.w * w3.w;
    }
  }

  float4 bb = *reinterpret_cast<const float4*>(bias + tc);
  if (PROJ) {
    float w4r[4][3];
    #pragma unroll
    for (int c = 0; c < 4; ++c) {
      w4r[c][0] = W4[(tc + c) * 3 + 0];
      w4r[c][1] = W4[(tc + c) * 3 + 1];
      w4r[c][2] = W4[(tc + c) * 3 + 2];
    }
    #pragma unroll
    for (int r = 0; r < 4; ++r) {
      int row = row0 + tr + r;
      float d = (row < n) ? dis[row] : 0.0f;
      float4 a = acc[r];
      a.x = silu_f(a.x + bb.x) * d;
      a.y = silu_f(a.y + bb.y) * d;
      a.z = silu_f(a.z + bb.z) * d;
      a.w = silu_f(a.w + bb.w) * d;
      float p0 = a.x * w4r[0][0] + a.y * w4r[1][0] + a.z * w4r[2][0] + a.w * w4r[3][0];
      float p1 = a.x * w4r[0][1] + a.y * w4r[1][1] + a.z * w4r[2][1] + a.w * w4r[3][1];
      float p2 = a.x * w4r[0][2] + a.y * w4r[1][2] + a.z * w4r[2][2] + a.w * w4r[3][2];
      #pragma unroll
      for (int m = 16; m >= 1; m >>= 1) {
        p0 += __shfl_xor(p0, m);
        p1 += __shfl_xor(p1, m);
        p2 += __shfl_xor(p2, m);
      }
      if ((t & 31) == 0 && row < n) {
        out[row * 3 + 0] = p0;
        out[row * 3 + 1] = p1;
        out[row * 3 + 2] = p2;
      }
    }
  } else {
    #pragma unroll
    for (int r = 0; r < 4; ++r) {
      int row = row0 + tr + r;
      if (row < n) {
        float4 a = acc[r];
        float d = dis[row];
        a.x = silu_f(a.x + bb.x) * d;
        a.y = silu_f(a.y + bb.y) * d;
        a.z = silu_f(a.z + bb.z) * d;
        a.w = silu_f(a.w + bb.w) * d;
        *reinterpret_cast<float4*>(out + (size_t)(tc >> 4) * slStride +
                                   (size_t)row * 16 + (tc & 15)) = a;
      }
    }
  }
}

extern "C" void kernel_launch(void* const* d_in, const int* in_sizes, int n_in,
                              void* d_out, int out_size, void* d_ws, size_t ws_size,
                              hipStream_t stream) {
  const float* pos = (const float*)d_in[0];
  const int* e32 = (const int*)d_in[1];
  const float* W[5] = {(const float*)d_in[2], (const float*)d_in[4], (const float*)d_in[6],
                       (const float*)d_in[8], (const float*)d_in[10]};
  const float* B[5] = {(const float*)d_in[3], (const float*)d_in[5], (const float*)d_in[7],
                       (const float*)d_in[9], (const float*)d_in[11]};
  float* out = (float*)d_out;

  const int N = in_sizes[0] / 3;
  const int E = in_sizes[1] / 2;
  const int NBUCKET = (N + (1 << BUCKET_SHIFT) - 1) >> BUCKET_SHIFT;  // 391
  const int M = NBUCKET * NB_SPLIT;
  const int chunk = (E + NB_SPLIT - 1) / NB_SPLIT;
  const int slStride = N * 16;           // floats per 16-col slice

  char* base = (char*)d_ws;
  size_t off = 0;
  auto alloc = [&](size_t bytes) -> void* {
    void* p = base + off;
    off += (bytes + 255) & ~(size_t)255;
    return p;
  };
  float* dis   = (float*)alloc((size_t)N * 4);
  int* rowp    = (int*)alloc((size_t)(N + 1) * 4);
  int* bsum2   = (int*)alloc(128 * 4);
  int* flag    = (int*)alloc(256);
  int* cnt2    = (int*)alloc((size_t)M * 4);
  int* off2    = (int*)alloc((size_t)M * 4);
  unsigned short* col = (unsigned short*)alloc((size_t)E * 2);
  float* y3    = (float*)alloc((size_t)N * 3 * 4);
  float* bufA  = (float*)alloc((size_t)N * 128 * 4);
  float* bufB  = (float*)alloc((size_t)N * 128 * 4);
  // epack/tmp only live during CSR build; alias the big activation buffers.
  int* epack = (int*)bufA;
  int* tmp   = (int*)bufB;

  const int nblk2 = (M + 1023) / 1024;   // 98

  // --- CSR build ---
  k_detect<<<1, 256, 0, stream>>>(e32, flag);
  k_prep<<<NB_SPLIT, 256, 0, stream>>>(e32, flag, epack, cnt2, E, NBUCKET, chunk);
  k_scan1<<<nblk2, 256, 0, stream>>>(cnt2, off2, bsum2, M);
  k_scan2<<<1, 64, 0, stream>>>(bsum2, nblk2);
  k_scanadd<<<(M + 255) / 256, 256, 0, stream>>>(off2, bsum2, M);
  k_split<<<NB_SPLIT, 256, 0, stream>>>(epack, off2, tmp, E, NBUCKET, chunk);
  k_csr<<<NBUCKET, 256, 0, stream>>>(tmp, off2, rowp, dis, col, E, NBUCKET, N);

  // --- layer 0: 3-dim aggregate (prescale fused) then 3->128 matmul ---
  k_agg3<1><<<(N + 255) / 256, 256, 0, stream>>>(pos, y3, rowp, col, dis, nullptr, N);
  k_mm0<<<(N * 32 + 255) / 256, 256, 0, stream>>>(y3, W[0], B[0], dis, bufA, N, slStride);

  // --- layers 1..2: sliced aggregate (128) then 128x128 matmul + SiLU + dis ---
  const int agg_grid = ((N + 31) / 32) * 8;
  const int mm_grid = (N + 63) / 64;
  for (int l = 1; l <= 2; ++l) {
    k_agg_slice<<<agg_grid, 256, 0, stream>>>(bufA, bufB, rowp, col, dis, N, slStride);
    k_mm_w<0><<<mm_grid, 512, 0, stream>>>(bufB, W[l], B[l], dis, bufA, nullptr, N, slStride);
  }

  // --- layer 3: aggregate, matmul fused with layer-4's 128->3 projection ---
  k_agg_slice<<<agg_grid, 256, 0, stream>>>(bufA, bufB, rowp, col, dis, N, slStride);
  k_mm_w<1><<<mm_grid, 512, 0, stream>>>(bufB, W[3], B[3], dis, y3, W[4], N, slStride);

  // --- layer 4: 3-dim aggregate + bias ---
  k_agg3<0><<<(N + 255) / 256, 256, 0, stream>>>(y3, out, rowp, col, dis, B[4], N);

  (void)n_in; (void)out_size; (void)ws_size;
}